// Round 17
// baseline (1723.846 us; speedup 1.0000x reference)
//
#include <hip/hip_runtime.h>
#include <hip/hip_bf16.h>
#include <cstdint>
#include <cstddef>

typedef __attribute__((ext_vector_type(4)))  float f32x4;
typedef __attribute__((ext_vector_type(8)))  short s16x8;
typedef __attribute__((ext_vector_type(8)))  unsigned short u16x8;
typedef __attribute__((ext_vector_type(4)))  unsigned short u16x4;
typedef unsigned short ushort_t;
typedef unsigned long long u64;

#define MFMA_BF16(a, b, c) __builtin_amdgcn_mfma_f32_16x16x32_bf16((a), (b), (c), 0, 0, 0)

constexpr int BATCH  = 4;
constexpr int SEQ    = 2048;
constexpr int NHEAD  = 16;
constexpr int HEADD  = 64;
constexpr int HID    = 1024;
constexpr int BH     = BATCH * NHEAD;   // 64
constexpr int MROWS  = BATCH * SEQ;     // 8192

// scale folded at Q epilogue: 1/sqrt(64) * log2(e)  (softmax in exp2 domain)
#define QSCALE 0.180336880091961f

// fp32 -> bf16 bits, RNE via compiler
__device__ __forceinline__ ushort_t f2bf(float f) {
  return __builtin_bit_cast(ushort_t, __float2bfloat16(f));
}

// Swizzled Ps offset (ushort elems): row stride 136; chunk XOR keeps both the
// scalar write side and the b128 read side <=2-way bank aliased.
__device__ __forceinline__ int ps_off(int q, int k) {       // Ps[q=0..127][k=0..127]
  return q * 136 + ((((k >> 3) ^ ((q >> 3) & 7)) & 15) << 3) + (k & 7);
}

// global(16B per lane) -> LDS, wave-uniform LDS base + lane*16
__device__ __forceinline__ void gl2lds16(const ushort_t* g, ushort_t* l) {
  __builtin_amdgcn_global_load_lds(
      (const __attribute__((address_space(1))) void*)g,
      (__attribute__((address_space(3))) void*)l, 16, 0, 0);
}

// K-tile fragment buffer: 8 j-slots x 2 halves = 64 VGPR
struct KFrag {
  s16x8 b0[8];
  s16x8 b1[8];
};

__device__ __forceinline__ void load_kfrag(KFrag& kf, const ushort_t* Kg,
                                           int kt, int lo, int hi) {
#pragma unroll
  for (int j = 0; j < 8; j++) {
    const ushort_t* kr = Kg + (size_t)(kt * 128 + j * 16 + lo) * HEADD + hi * 8;
    kf.b0[j] = *(const s16x8*)(kr);
    kf.b1[j] = *(const s16x8*)(kr + 32);
  }
}

// ---------------------------------------------------------------------------
// Prepack: z=0,1,2 -> convert X[z] (8.4M f32) and W[z] (1M f32) to bf16 (nt);
// z=3 -> mask bit-pack. Pure streaming. Verified good (R10-R16).
// ---------------------------------------------------------------------------
__global__ __launch_bounds__(256) void prepack_kernel(
    const float* __restrict__ q_in, const float* __restrict__ k_in,
    const float* __restrict__ v_in,
    const float* __restrict__ w_q, const float* __restrict__ w_k,
    const float* __restrict__ w_v,
    ushort_t* __restrict__ Xb, ushort_t* __restrict__ Wb,
    const int* __restrict__ mask, u64* __restrict__ pm) {
  const int z = blockIdx.z;
  if (z == 3) {
    const int nwords = BATCH * SEQ * SEQ / 64;  // 262144
    const int lane = threadIdx.x & 63;
    int wid = blockIdx.x * 4 + (threadIdx.x >> 6);
    const int step = gridDim.x * 4;
    for (; wid < nwords; wid += step) {
      int mv = __builtin_nontemporal_load(mask + (size_t)wid * 64 + lane);
      u64 bits = __ballot(mv != 0);
      if (lane == 0) pm[wid] = bits;
    }
    return;
  }
  const float* srcX = (z == 0) ? q_in : (z == 1) ? k_in : v_in;
  const float* srcW = (z == 0) ? w_q : (z == 1) ? w_k : w_v;
  ushort_t* dstX = Xb + (size_t)z * MROWS * HID;
  ushort_t* dstW = Wb + (size_t)z * HID * HID;

  const int tid = blockIdx.x * 256 + threadIdx.x;
  const int stride = gridDim.x * 256;

  for (int u = tid; u < MROWS * HID / 8; u += stride) {
    const float* s = srcX + (size_t)u * 8;
    f32x4 a = __builtin_nontemporal_load((const f32x4*)s);
    f32x4 b = __builtin_nontemporal_load((const f32x4*)(s + 4));
    u16x8 o = {f2bf(a[0]), f2bf(a[1]), f2bf(a[2]), f2bf(a[3]),
               f2bf(b[0]), f2bf(b[1]), f2bf(b[2]), f2bf(b[3])};
    __builtin_nontemporal_store(o, (u16x8*)(dstX + (size_t)u * 8));
  }
  for (int u = tid; u < HID * HID / 8; u += stride) {
    const float* s = srcW + (size_t)u * 8;
    f32x4 a = __builtin_nontemporal_load((const f32x4*)s);
    f32x4 b = __builtin_nontemporal_load((const f32x4*)(s + 4));
    u16x8 o = {f2bf(a[0]), f2bf(a[1]), f2bf(a[2]), f2bf(a[3]),
               f2bf(b[0]), f2bf(b[1]), f2bf(b[2]), f2bf(b[3])};
    __builtin_nontemporal_store(o, (u16x8*)(dstW + (size_t)u * 8));
  }
}

// ---------------------------------------------------------------------------
// Proj GEMM, m97-style + source-side XOR swizzle. Verified good (R12-R16).
// ---------------------------------------------------------------------------
__global__ __launch_bounds__(256, 4) void proj_gemm_kernel(
    const ushort_t* __restrict__ Xb, const ushort_t* __restrict__ Wb,
    const float* __restrict__ b_q, const float* __restrict__ b_k,
    const float* __restrict__ b_v,
    ushort_t* __restrict__ Qp, ushort_t* __restrict__ Kp,
    ushort_t* __restrict__ Vp) {
  __shared__ ushort_t As[128 * 64];
  __shared__ ushort_t Bs[128 * 64];

  const int z = blockIdx.z;
  const float* bias = (z == 0) ? b_q : (z == 1) ? b_k : b_v;
  const float scale = (z == 0) ? QSCALE : 1.0f;

  const int tid  = threadIdx.x;
  const int lane = tid & 63;
  const int wave = tid >> 6;
  const int wr = wave >> 1, wc = wave & 1;
  const int lo = lane & 15, hi = lane >> 4;
  const int mb = blockIdx.y, nb = blockIdx.x;

  const ushort_t* Ag = Xb + (size_t)z * MROWS * HID + (size_t)mb * 128 * HID;
  const ushort_t* Bg = Wb + (size_t)z * HID * HID + (size_t)nb * 128 * HID;
  const int lrow = lane >> 3;
  const int scol = (((lane & 7) ^ lrow) * 8);     // swizzled source col (elems)

  f32x4 acc[4][4];
#pragma unroll
  for (int i = 0; i < 4; i++)
#pragma unroll
    for (int j = 0; j < 4; j++) acc[i][j] = (f32x4){0.f, 0.f, 0.f, 0.f};

  for (int k0 = 0; k0 < HID; k0 += 64) {
#pragma unroll
    for (int it = 0; it < 4; it++) {
      const int r0 = (it * 4 + wave) * 8;
      gl2lds16(Ag + (size_t)(r0 + lrow) * HID + k0 + scol, &As[(it * 4 + wave) * 512]);
      gl2lds16(Bg + (size_t)(r0 + lrow) * HID + k0 + scol, &Bs[(it * 4 + wave) * 512]);
    }
    __syncthreads();
#pragma unroll
    for (int kk = 0; kk < 2; kk++) {
      const int pu = (((kk * 4 + hi) ^ (lo & 7)) * 8);
      s16x8 af[4], bf[4];
#pragma unroll
      for (int i = 0; i < 4; i++)
        af[i] = *(const s16x8*)(&As[(wr * 64 + i * 16 + lo) * 64 + pu]);
#pragma unroll
      for (int j = 0; j < 4; j++)
        bf[j] = *(const s16x8*)(&Bs[(wc * 64 + j * 16 + lo) * 64 + pu]);
#pragma unroll
      for (int i = 0; i < 4; i++)
#pragma unroll
        for (int j = 0; j < 4; j++)
          acc[i][j] = MFMA_BF16(af[i], bf[j], acc[i][j]);
    }
    __syncthreads();
  }

  if (z != 2) {
    ushort_t* out = (z == 0) ? Qp : Kp;
#pragma unroll
    for (int j = 0; j < 4; j++) {
      const int n = nb * 128 + wc * 64 + j * 16 + lo;
      const float bvn = bias[n];
      const int h = n >> 6, d = n & 63;
#pragma unroll
      for (int i = 0; i < 4; i++) {
        const int m0 = mb * 128 + wr * 64 + i * 16 + hi * 4;
#pragma unroll
        for (int r = 0; r < 4; r++) {
          const int m = m0 + r;
          const int b = m >> 11, s = m & 2047;
          float v = (acc[i][j][r] + bvn) * scale;
          __builtin_nontemporal_store(
              f2bf(v), out + (((size_t)(b * NHEAD + h) * SEQ) + s) * HEADD + d);
        }
      }
    }
  } else {
#pragma unroll
    for (int j = 0; j < 4; j++) {
      const int n = nb * 128 + wc * 64 + j * 16 + lo;
      const float bvn = bias[n];
      const int h = n >> 6, d = n & 63;
#pragma unroll
      for (int i = 0; i < 4; i++) {
        const int m0 = mb * 128 + wr * 64 + i * 16 + hi * 4;
        const int b = m0 >> 11, s0 = m0 & 2047;
        u16x4 pk = {f2bf(acc[i][j][0] + bvn), f2bf(acc[i][j][1] + bvn),
                    f2bf(acc[i][j][2] + bvn), f2bf(acc[i][j][3] + bvn)};
        __builtin_nontemporal_store(
            pk, (u16x4*)(Vp + ((size_t)(b * NHEAD + h) * HEADD + d) * SEQ + s0));
      }
    }
  }
}

// ---------------------------------------------------------------------------
// Fused attention — R14 structure (verified best) + K-tile register
// prefetch pipeline (ping-pong KFrag, unroll-by-2; barriers and all access
// patterns byte-identical; only load ISSUE TIME moves one tile earlier).
// LDS is the occupancy binder (2 blocks/CU), so the +128 VGPR of the two
// KFrag buffers is free.
// ---------------------------------------------------------------------------
__device__ __forceinline__ void sweep1_tile(
    const KFrag& kf, KFrag& kn, int kt, int ktn,
    const ushort_t* Kg, const ushort_t* Vg, ushort_t* Vt, ushort_t* Ps,
    const u64* pmb, int q0, int lane, int wave,
    const s16x8 (&aq)[2][2], float (&lrun)[2][4], f32x4 (&pacc)[2][4]) {
  const int lo = lane & 15, hi = lane >> 4;
  const int vr16 = wave * 4 + (lane >> 4);
  const int vc8  = (lane & 15) * 8;

  u16x8 vreg[4];
#pragma unroll
  for (int it = 0; it < 4; it++)
    vreg[it] = *(const u16x8*)(Vg + (size_t)(it * 16 + vr16) * SEQ + kt * 128 + vc8);

  f32x4 sacc[2][8];
#pragma unroll
  for (int i = 0; i < 2; i++)
#pragma unroll
    for (int j = 0; j < 8; j++) sacc[i][j] = (f32x4){0.f, 0.f, 0.f, 0.f};
#pragma unroll
  for (int j = 0; j < 8; j++) {
    sacc[0][j] = MFMA_BF16(aq[0][0], kf.b0[j], sacc[0][j]);
    sacc[1][j] = MFMA_BF16(aq[1][0], kf.b0[j], sacc[1][j]);
    sacc[0][j] = MFMA_BF16(aq[0][1], kf.b1[j], sacc[0][j]);
    sacc[1][j] = MFMA_BF16(aq[1][1], kf.b1[j], sacc[1][j]);
  }

  // prefetch next K tile: latency hides under softmax + barrier + PV
  load_kfrag(kn, Kg, ktn, lo, hi);

  // commit V tile to LDS (coalesced u16x8, <=2-way banks)
#pragma unroll
  for (int it = 0; it < 4; it++)
    *(u16x8*)(&Vt[(it * 16 + vr16) * 136 + vc8]) = vreg[it];

  // e = exp2(masked s); lane-local row partial sums; Ps <- bf16(e)
#pragma unroll
  for (int i = 0; i < 2; i++)
#pragma unroll
    for (int r = 0; r < 4; r++) {
      const int q = q0 + i * 16 + hi * 4 + r;
      const u64* pw = pmb + (size_t)q * 32 + kt * 2;
      u64 s0 = pw[0] >> lo, s1 = pw[1] >> lo;
      const int prow = wave * 32 + i * 16 + hi * 4 + r;
      float tsum = 0.f;
#pragma unroll
      for (int j = 0; j < 8; j++) {
        unsigned bit = (unsigned)((j < 4 ? (s0 >> (j * 16)) : (s1 >> ((j - 4) * 16))) & 1ull);
        float s = bit ? sacc[i][j][r] : -1e30f;
        float ev = __builtin_amdgcn_exp2f(s);
        tsum += ev;
        Ps[ps_off(prow, j * 16 + lo)] = f2bf(ev);
      }
      lrun[i][r] += tsum;
    }
  __syncthreads();   // Ps + Vt visible

  // PV: pacc += E @ V  (unnormalized)
#pragma unroll
  for (int kkp = 0; kkp < 4; kkp++) {
    const int ko = kkp * 32 + hi * 8;
    s16x8 ap0 = *(const s16x8*)(&Ps[ps_off(wave * 32 + lo, ko)]);
    s16x8 ap1 = *(const s16x8*)(&Ps[ps_off(wave * 32 + 16 + lo, ko)]);
#pragma unroll
    for (int jd = 0; jd < 4; jd++) {
      s16x8 bv = *(const s16x8*)(&Vt[(jd * 16 + lo) * 136 + ko]);
      pacc[0][jd] = MFMA_BF16(ap0, bv, pacc[0][jd]);
      pacc[1][jd] = MFMA_BF16(ap1, bv, pacc[1][jd]);
    }
  }
  __syncthreads();   // Ps/Vt consumed before next tile's staging
}

__device__ __forceinline__ void sweep2_tile(
    const KFrag& kf, KFrag& kn, int kt, int ktn,
    const ushort_t* Kg, float* stg, const float* mi_w,
    const u64* pmb, int q0, int lane, int wave, int bh,
    const s16x8 (&aq)[2][2], float* attn) {
  const int lo = lane & 15, hi = lane >> 4;

  f32x4 sacc[2][8];
#pragma unroll
  for (int i = 0; i < 2; i++)
#pragma unroll
    for (int j = 0; j < 8; j++) sacc[i][j] = (f32x4){0.f, 0.f, 0.f, 0.f};
#pragma unroll
  for (int j = 0; j < 8; j++) {
    sacc[0][j] = MFMA_BF16(aq[0][0], kf.b0[j], sacc[0][j]);
    sacc[1][j] = MFMA_BF16(aq[1][0], kf.b0[j], sacc[1][j]);
    sacc[0][j] = MFMA_BF16(aq[0][1], kf.b1[j], sacc[0][j]);
    sacc[1][j] = MFMA_BF16(aq[1][1], kf.b1[j], sacc[1][j]);
  }

  // prefetch next K tile: latency hides under the repack + store phase
  load_kfrag(kn, Kg, ktn, lo, hi);

#pragma unroll
  for (int hh = 0; hh < 2; hh++) {
    // Phase A: stage raw scores row-major [32][65] (wave-private; in-wave
    // DS ordering + compiler lgkmcnt handles RAW/WAR, no barrier needed)
#pragma unroll
    for (int i = 0; i < 2; i++)
#pragma unroll
      for (int j4 = 0; j4 < 4; j4++)
#pragma unroll
        for (int r = 0; r < 4; r++)
          stg[(i * 16 + hi * 4 + r) * 65 + j4 * 16 + lo] = sacc[i][hh * 4 + j4][r];
    // Phase B: one row per iteration; 64 lanes = 256B contiguous store
#pragma unroll
    for (int rl = 0; rl < 32; rl++) {
      const int q = q0 + rl;
      const float s = stg[rl * 65 + lane];
      const u64 w = pmb[(size_t)q * 32 + kt * 2 + hh];
      const float miv = mi_w[rl];
      const float e =
          ((w >> lane) & 1ull) ? __builtin_amdgcn_exp2f(s - miv) : 0.f;
      __builtin_nontemporal_store(
          e, attn + ((size_t)bh * SEQ + q) * SEQ + kt * 128 + hh * 64 + lane);
    }
  }
}

__global__ __launch_bounds__(256, 2) void fused_attn_kernel(
    const ushort_t* __restrict__ Qp, const ushort_t* __restrict__ Kp,
    const ushort_t* __restrict__ Vtg, const u64* __restrict__ pm,
    float* __restrict__ attn, float* __restrict__ ctx) {
  extern __shared__ ushort_t smem[];
  ushort_t* Vt = smem;           // [64][136] linear+pad  = 8704 elems
  ushort_t* Ps = smem + 8704;    // [128][136] swizzled   = 17408 elems
  // sweep2 aliases (used only after sweep1's final barrier):
  float* stgf   = (float*)smem;            // 4 x [32][65] f32 = 33280 B
  float* mi_lds = stgf + 4 * 2080;         // 128 f32 (wave-private slices)

  const int tid  = threadIdx.x;
  const int lane = tid & 63, wave = tid >> 6;
  const int lo = lane & 15, hi = lane >> 4;

  const int f   = blockIdx.x;                 // 0..1023
  const int xcd = f & 7, i5 = f >> 3;         // i5: 0..127
  const int bh  = xcd * 8 + (i5 & 7);
  const int qb  = i5 >> 3;                    // 0..15
  const int b = bh >> 4, h = bh & 15;

  const ushort_t* Qg = Qp + ((size_t)bh * SEQ + qb * 128 + wave * 32) * HEADD;
  s16x8 aq[2][2];
#pragma unroll
  for (int i = 0; i < 2; i++)
#pragma unroll
    for (int kk = 0; kk < 2; kk++)
      aq[i][kk] = *(const s16x8*)(Qg + (size_t)(i * 16 + lo) * HEADD + kk * 32 + hi * 8);

  const ushort_t* Kg = Kp + (size_t)bh * SEQ * HEADD;          // [s][d]
  const ushort_t* Vg = Vtg + (size_t)bh * HEADD * SEQ;         // [d][s]
  const u64* pmb = pm + (size_t)b * SEQ * 32;
  const int q0 = qb * 128 + wave * 32;

  float lrun[2][4];
#pragma unroll
  for (int i = 0; i < 2; i++)
#pragma unroll
    for (int r = 0; r < 4; r++) lrun[i][r] = 0.f;
  f32x4 pacc[2][4];
#pragma unroll
  for (int i = 0; i < 2; i++)
#pragma unroll
    for (int jd = 0; jd < 4; jd++) pacc[i][jd] = (f32x4){0.f, 0.f, 0.f, 0.f};

  // ============ sweep 1: l + PV, K-prefetch ping-pong ============
  KFrag kfA, kfB;
  load_kfrag(kfA, Kg, 0, lo, hi);
  for (int kt = 0; kt < SEQ / 128; kt += 2) {
    sweep1_tile(kfA, kfB, kt, kt + 1, Kg, Vg, Vt, Ps, pmb, q0, lane, wave,
                aq, lrun, pacc);
    sweep1_tile(kfB, kfA, kt + 1, (kt + 2) & 15, Kg, Vg, Vt, Ps, pmb, q0,
                lane, wave, aq, lrun, pacc);
  }

  // ---- finalize: l, ctx = pacc/l (nt), mi -> wave-private LDS ----
  float il[2][4];
#pragma unroll
  for (int i = 0; i < 2; i++)
#pragma unroll
    for (int r = 0; r < 4; r++) {
      float l = lrun[i][r];
#pragma unroll
      for (int off = 1; off < 16; off <<= 1) l += __shfl_xor(l, off);
      il[i][r] = 1.0f / l;
      if (lo == 0)
        mi_lds[wave * 32 + i * 16 + hi * 4 + r] = __builtin_amdgcn_logf(l);  // log2
    }
#pragma unroll
  for (int i = 0; i < 2; i++)
#pragma unroll
    for (int jd = 0; jd < 4; jd++)
#pragma unroll
      for (int r = 0; r < 4; r++) {
        const int q = q0 + i * 16 + hi * 4 + r;
        __builtin_nontemporal_store(
            pacc[i][jd][r] * il[i][r],
            ctx + ((size_t)b * SEQ + q) * HID + h * HEADD + jd * 16 + lo);
      }
  // (last sweep1_tile ended with __syncthreads(): Ps/Vt fully consumed; the
  // stgf alias below is wave-private, so no extra barrier is required before
  // aliasing — matches R14's verified behavior.)

  // ===== sweep 2: attn stores, K-prefetch ping-pong =====
  float* stg = stgf + wave * 2080;   // [32][65] f32, wave-private
  const float* mi_w = mi_lds + wave * 32;
  load_kfrag(kfA, Kg, 0, lo, hi);
  for (int kt = 0; kt < SEQ / 128; kt += 2) {
    sweep2_tile(kfA, kfB, kt, kt + 1, Kg, stg, mi_w, pmb, q0, lane, wave, bh,
                aq, attn);
    sweep2_tile(kfB, kfA, kt + 1, (kt + 2) & 15, Kg, stg, mi_w, pmb, q0, lane,
                wave, bh, aq, attn);
  }
}

// ---------------------------------------------------------------------------
extern "C" void kernel_launch(void* const* d_in, const int* in_sizes, int n_in,
                              void* d_out, int out_size, void* d_ws, size_t ws_size,
                              hipStream_t stream) {
  const float* query  = (const float*)d_in[0];
  const float* key_in = (const float*)d_in[1];
  const float* value  = (const float*)d_in[2];
  const int*   mask   = (const int*)d_in[3];
  const float* w_q = (const float*)d_in[4];
  const float* b_q = (const float*)d_in[5];
  const float* w_k = (const float*)d_in[6];
  const float* b_k = (const float*)d_in[7];
  const float* w_v = (const float*)d_in[8];
  const float* b_v = (const float*)d_in[9];

  char* ws = (char*)d_ws;
  const size_t proj_elems = (size_t)BATCH * NHEAD * SEQ * HEADD;  // 8388608
  ushort_t* Qp = (ushort_t*)ws;
  ushort_t* Kp = Qp + proj_elems;
  ushort_t* Vp = Kp + proj_elems;          // [B][H][D][S] transposed
  u64* pmask   = (u64*)(ws + 3 * proj_elems * sizeof(ushort_t));

  float* ctx  = (float*)d_out;                         // [B][S][HID]
  float* attn = ctx + (size_t)BATCH * SEQ * HID;       // [B][H][S][S]

  // bf16 prepack scratch lives in d_out's attn region (read by the GEMM,
  // overwritten afterwards by the attn kernel). Sequential + deterministic.
  ushort_t* Xb = (ushort_t*)attn;                         // 3 x 8.4M bf16
  ushort_t* Wb = Xb + (size_t)3 * MROWS * HID;            // 3 x 1M bf16

  prepack_kernel<<<dim3(512, 1, 4), dim3(256), 0, stream>>>(
      query, key_in, value, w_q, w_k, w_v, Xb, Wb, mask, pmask);

  proj_gemm_kernel<<<dim3(HID / 128, MROWS / 128, 3), dim3(256), 0, stream>>>(
      Xb, Wb, b_q, b_k, b_v, Qp, Kp, Vp);

  const size_t lds_attn = (8704 + 17408) * sizeof(ushort_t);  // 52224 B
  fused_attn_kernel<<<dim3(BH * (SEQ / 128)), dim3(256), lds_attn, stream>>>(
      Qp, Kp, Vp, pmask, attn, ctx);
}

// Round 18
// 666.691 us; speedup vs baseline: 2.5857x; 2.5857x over previous
//
#include <hip/hip_runtime.h>
#include <hip/hip_bf16.h>
#include <cstdint>
#include <cstddef>

typedef __attribute__((ext_vector_type(4)))  float f32x4;
typedef __attribute__((ext_vector_type(8)))  short s16x8;
typedef __attribute__((ext_vector_type(8)))  unsigned short u16x8;
typedef __attribute__((ext_vector_type(4)))  unsigned short u16x4;
typedef unsigned short ushort_t;
typedef unsigned long long u64;

#define MFMA_BF16(a, b, c) __builtin_amdgcn_mfma_f32_16x16x32_bf16((a), (b), (c), 0, 0, 0)

constexpr int BATCH  = 4;
constexpr int SEQ    = 2048;
constexpr int NHEAD  = 16;
constexpr int HEADD  = 64;
constexpr int HID    = 1024;
constexpr int BH     = BATCH * NHEAD;   // 64
constexpr int MROWS  = BATCH * SEQ;     // 8192

// scale folded at Q epilogue: 1/sqrt(64) * log2(e)  (softmax in exp2 domain)
#define QSCALE 0.180336880091961f

// fp32 -> bf16 bits, RNE via compiler
__device__ __forceinline__ ushort_t f2bf(float f) {
  return __builtin_bit_cast(ushort_t, __float2bfloat16(f));
}

// Swizzled Ps offset (ushort elems): row stride 136; chunk XOR keeps both the
// scalar write side and the b128 read side <=2-way bank aliased.
__device__ __forceinline__ int ps_off(int q, int k) {       // Ps[q=0..127][k=0..127]
  return q * 136 + ((((k >> 3) ^ ((q >> 3) & 7)) & 15) << 3) + (k & 7);
}

// global(16B per lane) -> LDS, wave-uniform LDS base + lane*16
__device__ __forceinline__ void gl2lds16(const ushort_t* g, ushort_t* l) {
  __builtin_amdgcn_global_load_lds(
      (const __attribute__((address_space(1))) void*)g,
      (__attribute__((address_space(3))) void*)l, 16, 0, 0);
}

// ---------------------------------------------------------------------------
// Prepack: z=0,1,2 -> convert X[z] (8.4M f32) and W[z] (1M f32) to bf16 (nt);
// z=3 -> mask bit-pack. Pure streaming. Verified good (R10-R16).
// ---------------------------------------------------------------------------
__global__ __launch_bounds__(256) void prepack_kernel(
    const float* __restrict__ q_in, const float* __restrict__ k_in,
    const float* __restrict__ v_in,
    const float* __restrict__ w_q, const float* __restrict__ w_k,
    const float* __restrict__ w_v,
    ushort_t* __restrict__ Xb, ushort_t* __restrict__ Wb,
    const int* __restrict__ mask, u64* __restrict__ pm) {
  const int z = blockIdx.z;
  if (z == 3) {
    const int nwords = BATCH * SEQ * SEQ / 64;  // 262144
    const int lane = threadIdx.x & 63;
    int wid = blockIdx.x * 4 + (threadIdx.x >> 6);
    const int step = gridDim.x * 4;
    for (; wid < nwords; wid += step) {
      int mv = __builtin_nontemporal_load(mask + (size_t)wid * 64 + lane);
      u64 bits = __ballot(mv != 0);
      if (lane == 0) pm[wid] = bits;
    }
    return;
  }
  const float* srcX = (z == 0) ? q_in : (z == 1) ? k_in : v_in;
  const float* srcW = (z == 0) ? w_q : (z == 1) ? w_k : w_v;
  ushort_t* dstX = Xb + (size_t)z * MROWS * HID;
  ushort_t* dstW = Wb + (size_t)z * HID * HID;

  const int tid = blockIdx.x * 256 + threadIdx.x;
  const int stride = gridDim.x * 256;

  for (int u = tid; u < MROWS * HID / 8; u += stride) {
    const float* s = srcX + (size_t)u * 8;
    f32x4 a = __builtin_nontemporal_load((const f32x4*)s);
    f32x4 b = __builtin_nontemporal_load((const f32x4*)(s + 4));
    u16x8 o = {f2bf(a[0]), f2bf(a[1]), f2bf(a[2]), f2bf(a[3]),
               f2bf(b[0]), f2bf(b[1]), f2bf(b[2]), f2bf(b[3])};
    __builtin_nontemporal_store(o, (u16x8*)(dstX + (size_t)u * 8));
  }
  for (int u = tid; u < HID * HID / 8; u += stride) {
    const float* s = srcW + (size_t)u * 8;
    f32x4 a = __builtin_nontemporal_load((const f32x4*)s);
    f32x4 b = __builtin_nontemporal_load((const f32x4*)(s + 4));
    u16x8 o = {f2bf(a[0]), f2bf(a[1]), f2bf(a[2]), f2bf(a[3]),
               f2bf(b[0]), f2bf(b[1]), f2bf(b[2]), f2bf(b[3])};
    __builtin_nontemporal_store(o, (u16x8*)(dstW + (size_t)u * 8));
  }
}

// ---------------------------------------------------------------------------
// Proj GEMM, m97-style + source-side XOR swizzle. Verified good (R12-R16).
// ---------------------------------------------------------------------------
__global__ __launch_bounds__(256, 4) void proj_gemm_kernel(
    const ushort_t* __restrict__ Xb, const ushort_t* __restrict__ Wb,
    const float* __restrict__ b_q, const float* __restrict__ b_k,
    const float* __restrict__ b_v,
    ushort_t* __restrict__ Qp, ushort_t* __restrict__ Kp,
    ushort_t* __restrict__ Vp) {
  __shared__ ushort_t As[128 * 64];
  __shared__ ushort_t Bs[128 * 64];

  const int z = blockIdx.z;
  const float* bias = (z == 0) ? b_q : (z == 1) ? b_k : b_v;
  const float scale = (z == 0) ? QSCALE : 1.0f;

  const int tid  = threadIdx.x;
  const int lane = tid & 63;
  const int wave = tid >> 6;
  const int wr = wave >> 1, wc = wave & 1;
  const int lo = lane & 15, hi = lane >> 4;
  const int mb = blockIdx.y, nb = blockIdx.x;

  const ushort_t* Ag = Xb + (size_t)z * MROWS * HID + (size_t)mb * 128 * HID;
  const ushort_t* Bg = Wb + (size_t)z * HID * HID + (size_t)nb * 128 * HID;
  const int lrow = lane >> 3;
  const int scol = (((lane & 7) ^ lrow) * 8);     // swizzled source col (elems)

  f32x4 acc[4][4];
#pragma unroll
  for (int i = 0; i < 4; i++)
#pragma unroll
    for (int j = 0; j < 4; j++) acc[i][j] = (f32x4){0.f, 0.f, 0.f, 0.f};

  for (int k0 = 0; k0 < HID; k0 += 64) {
#pragma unroll
    for (int it = 0; it < 4; it++) {
      const int r0 = (it * 4 + wave) * 8;
      gl2lds16(Ag + (size_t)(r0 + lrow) * HID + k0 + scol, &As[(it * 4 + wave) * 512]);
      gl2lds16(Bg + (size_t)(r0 + lrow) * HID + k0 + scol, &Bs[(it * 4 + wave) * 512]);
    }
    __syncthreads();
#pragma unroll
    for (int kk = 0; kk < 2; kk++) {
      const int pu = (((kk * 4 + hi) ^ (lo & 7)) * 8);
      s16x8 af[4], bf[4];
#pragma unroll
      for (int i = 0; i < 4; i++)
        af[i] = *(const s16x8*)(&As[(wr * 64 + i * 16 + lo) * 64 + pu]);
#pragma unroll
      for (int j = 0; j < 4; j++)
        bf[j] = *(const s16x8*)(&Bs[(wc * 64 + j * 16 + lo) * 64 + pu]);
#pragma unroll
      for (int i = 0; i < 4; i++)
#pragma unroll
        for (int j = 0; j < 4; j++)
          acc[i][j] = MFMA_BF16(af[i], bf[j], acc[i][j]);
    }
    __syncthreads();
  }

  if (z != 2) {
    ushort_t* out = (z == 0) ? Qp : Kp;
#pragma unroll
    for (int j = 0; j < 4; j++) {
      const int n = nb * 128 + wc * 64 + j * 16 + lo;
      const float bvn = bias[n];
      const int h = n >> 6, d = n & 63;
#pragma unroll
      for (int i = 0; i < 4; i++) {
        const int m0 = mb * 128 + wr * 64 + i * 16 + hi * 4;
#pragma unroll
        for (int r = 0; r < 4; r++) {
          const int m = m0 + r;
          const int b = m >> 11, s = m & 2047;
          float v = (acc[i][j][r] + bvn) * scale;
          __builtin_nontemporal_store(
              f2bf(v), out + (((size_t)(b * NHEAD + h) * SEQ) + s) * HEADD + d);
        }
      }
    }
  } else {
#pragma unroll
    for (int j = 0; j < 4; j++) {
      const int n = nb * 128 + wc * 64 + j * 16 + lo;
      const float bvn = bias[n];
      const int h = n >> 6, d = n & 63;
#pragma unroll
      for (int i = 0; i < 4; i++) {
        const int m0 = mb * 128 + wr * 64 + i * 16 + hi * 4;
        const int b = m0 >> 11, s0 = m0 & 2047;
        u16x4 pk = {f2bf(acc[i][j][0] + bvn), f2bf(acc[i][j][1] + bvn),
                    f2bf(acc[i][j][2] + bvn), f2bf(acc[i][j][3] + bvn)};
        __builtin_nontemporal_store(
            pk, (u16x4*)(Vp + ((size_t)(b * NHEAD + h) * HEADD + d) * SEQ + s0));
      }
    }
  }
}

// ---------------------------------------------------------------------------
// Fused attention — R14 verbatim (verified best, 668 us total, twice).
// Sweep1: barriered, Vt-staged PV (barriers are load-bearing: phase-lock
// keeps K/V reads L2-coherent and nt stores full-line — R15/R17 counters).
// Sweep2: LDS-repacked 256B-contiguous attn stores.
// ---------------------------------------------------------------------------
__global__ __launch_bounds__(256, 2) void fused_attn_kernel(
    const ushort_t* __restrict__ Qp, const ushort_t* __restrict__ Kp,
    const ushort_t* __restrict__ Vtg, const u64* __restrict__ pm,
    float* __restrict__ attn, float* __restrict__ ctx) {
  extern __shared__ ushort_t smem[];
  ushort_t* Vt = smem;           // [64][136] linear+pad  = 8704 elems
  ushort_t* Ps = smem + 8704;    // [128][136] swizzled   = 17408 elems
  // sweep2 aliases (used only after sweep1's final barrier):
  float* stgf   = (float*)smem;            // 4 x [32][65] f32 = 33280 B
  float* mi_lds = stgf + 4 * 2080;         // 128 f32 (wave-private slices)

  const int tid  = threadIdx.x;
  const int lane = tid & 63, wave = tid >> 6;
  const int lo = lane & 15, hi = lane >> 4;

  const int f   = blockIdx.x;                 // 0..1023
  const int xcd = f & 7, i5 = f >> 3;         // i5: 0..127
  const int bh  = xcd * 8 + (i5 & 7);
  const int qb  = i5 >> 3;                    // 0..15
  const int b = bh >> 4, h = bh & 15;

  const ushort_t* Qg = Qp + ((size_t)bh * SEQ + qb * 128 + wave * 32) * HEADD;
  s16x8 aq[2][2];
#pragma unroll
  for (int i = 0; i < 2; i++)
#pragma unroll
    for (int kk = 0; kk < 2; kk++)
      aq[i][kk] = *(const s16x8*)(Qg + (size_t)(i * 16 + lo) * HEADD + kk * 32 + hi * 8);

  const ushort_t* Kg = Kp + (size_t)bh * SEQ * HEADD;          // [s][d]
  const ushort_t* Vg = Vtg + (size_t)bh * HEADD * SEQ;         // [d][s]
  const u64* pmb = pm + (size_t)b * SEQ * 32;
  const int q0 = qb * 128 + wave * 32;

  float lrun[2][4];
#pragma unroll
  for (int i = 0; i < 2; i++)
#pragma unroll
    for (int r = 0; r < 4; r++) lrun[i][r] = 0.f;
  f32x4 pacc[2][4];
#pragma unroll
  for (int i = 0; i < 2; i++)
#pragma unroll
    for (int jd = 0; jd < 4; jd++) pacc[i][jd] = (f32x4){0.f, 0.f, 0.f, 0.f};

  const int vr16 = tid >> 4;         // 0..15 (V d-row base)
  const int vc8  = (tid & 15) * 8;   // 0..120 (V s-col)

  // ================= sweep 1: l + PV (unnormalized) =================
  for (int kt = 0; kt < SEQ / 128; kt++) {
    u16x8 vreg[4];
#pragma unroll
    for (int it = 0; it < 4; it++)
      vreg[it] = *(const u16x8*)(Vg + (size_t)(it * 16 + vr16) * SEQ + kt * 128 + vc8);

    f32x4 sacc[2][8];
#pragma unroll
    for (int i = 0; i < 2; i++)
#pragma unroll
      for (int j = 0; j < 8; j++) sacc[i][j] = (f32x4){0.f, 0.f, 0.f, 0.f};
#pragma unroll
    for (int j = 0; j < 8; j++) {
      const ushort_t* kr = Kg + (size_t)(kt * 128 + j * 16 + lo) * HEADD + hi * 8;
      s16x8 b0 = *(const s16x8*)(kr);
      s16x8 b1 = *(const s16x8*)(kr + 32);
      sacc[0][j] = MFMA_BF16(aq[0][0], b0, sacc[0][j]);
      sacc[1][j] = MFMA_BF16(aq[1][0], b0, sacc[1][j]);
      sacc[0][j] = MFMA_BF16(aq[0][1], b1, sacc[0][j]);
      sacc[1][j] = MFMA_BF16(aq[1][1], b1, sacc[1][j]);
    }

#pragma unroll
    for (int it = 0; it < 4; it++)
      *(u16x8*)(&Vt[(it * 16 + vr16) * 136 + vc8]) = vreg[it];

#pragma unroll
    for (int i = 0; i < 2; i++)
#pragma unroll
      for (int r = 0; r < 4; r++) {
        const int q = q0 + i * 16 + hi * 4 + r;
        const u64* pw = pmb + (size_t)q * 32 + kt * 2;
        u64 s0 = pw[0] >> lo, s1 = pw[1] >> lo;
        const int prow = wave * 32 + i * 16 + hi * 4 + r;
        float tsum = 0.f;
#pragma unroll
        for (int j = 0; j < 8; j++) {
          unsigned bit = (unsigned)((j < 4 ? (s0 >> (j * 16)) : (s1 >> ((j - 4) * 16))) & 1ull);
          float s = bit ? sacc[i][j][r] : -1e30f;
          float ev = __builtin_amdgcn_exp2f(s);
          tsum += ev;
          Ps[ps_off(prow, j * 16 + lo)] = f2bf(ev);
        }
        lrun[i][r] += tsum;
      }
    __syncthreads();   // Ps + Vt visible

#pragma unroll
    for (int kkp = 0; kkp < 4; kkp++) {
      const int ko = kkp * 32 + hi * 8;
      s16x8 ap0 = *(const s16x8*)(&Ps[ps_off(wave * 32 + lo, ko)]);
      s16x8 ap1 = *(const s16x8*)(&Ps[ps_off(wave * 32 + 16 + lo, ko)]);
#pragma unroll
      for (int jd = 0; jd < 4; jd++) {
        s16x8 bv = *(const s16x8*)(&Vt[(jd * 16 + lo) * 136 + ko]);
        pacc[0][jd] = MFMA_BF16(ap0, bv, pacc[0][jd]);
        pacc[1][jd] = MFMA_BF16(ap1, bv, pacc[1][jd]);
      }
    }
    __syncthreads();   // Ps/Vt consumed; after final iter all waves are past
  }                    // LDS use -> safe to alias stgf/mi_lds (wave-private)

  // ---- finalize: l, ctx = pacc/l (nt), mi -> wave-private LDS ----
  float il[2][4];
#pragma unroll
  for (int i = 0; i < 2; i++)
#pragma unroll
    for (int r = 0; r < 4; r++) {
      float l = lrun[i][r];
#pragma unroll
      for (int off = 1; off < 16; off <<= 1) l += __shfl_xor(l, off);
      il[i][r] = 1.0f / l;
      if (lo == 0)
        mi_lds[wave * 32 + i * 16 + hi * 4 + r] = __builtin_amdgcn_logf(l);  // log2
    }
#pragma unroll
  for (int i = 0; i < 2; i++)
#pragma unroll
    for (int jd = 0; jd < 4; jd++)
#pragma unroll
      for (int r = 0; r < 4; r++) {
        const int q = q0 + i * 16 + hi * 4 + r;
        __builtin_nontemporal_store(
            pacc[i][jd][r] * il[i][r],
            ctx + ((size_t)b * SEQ + q) * HID + h * HEADD + jd * 16 + lo);
      }

  // ===== sweep 2: attn = exp2(s - mi), LDS-repacked 256B-contiguous stores ==
  float* stg = stgf + wave * 2080;   // [32][65] f32, wave-private
  for (int kt = 0; kt < SEQ / 128; kt++) {
    f32x4 sacc[2][8];
#pragma unroll
    for (int i = 0; i < 2; i++)
#pragma unroll
      for (int j = 0; j < 8; j++) sacc[i][j] = (f32x4){0.f, 0.f, 0.f, 0.f};
#pragma unroll
    for (int j = 0; j < 8; j++) {
      const ushort_t* kr = Kg + (size_t)(kt * 128 + j * 16 + lo) * HEADD + hi * 8;
      s16x8 b0 = *(const s16x8*)(kr);
      s16x8 b1 = *(const s16x8*)(kr + 32);
      sacc[0][j] = MFMA_BF16(aq[0][0], b0, sacc[0][j]);
      sacc[1][j] = MFMA_BF16(aq[1][0], b0, sacc[1][j]);
      sacc[0][j] = MFMA_BF16(aq[0][1], b1, sacc[0][j]);
      sacc[1][j] = MFMA_BF16(aq[1][1], b1, sacc[1][j]);
    }
#pragma unroll
    for (int hh = 0; hh < 2; hh++) {
      // Phase A: stage raw scores row-major [32][65] (wave-private; in-wave
      // DS ordering + compiler lgkmcnt handles RAW/WAR, no barrier needed)
#pragma unroll
      for (int i = 0; i < 2; i++)
#pragma unroll
        for (int j4 = 0; j4 < 4; j4++)
#pragma unroll
          for (int r = 0; r < 4; r++)
            stg[(i * 16 + hi * 4 + r) * 65 + j4 * 16 + lo] = sacc[i][hh * 4 + j4][r];
      // Phase B: one row per iteration; 64 lanes = 256B contiguous store
#pragma unroll
      for (int rl = 0; rl < 32; rl++) {
        const int q = q0 + rl;
        const float s = stg[rl * 65 + lane];
        const u64 w = pmb[(size_t)q * 32 + kt * 2 + hh];
        const float miv = mi_lds[wave * 32 + rl];
        const float e =
            ((w >> lane) & 1ull) ? __builtin_amdgcn_exp2f(s - miv) : 0.f;
        __builtin_nontemporal_store(
            e, attn + ((size_t)bh * SEQ + q) * SEQ + kt * 128 + hh * 64 + lane);
      }
    }
  }
}

// ---------------------------------------------------------------------------
extern "C" void kernel_launch(void* const* d_in, const int* in_sizes, int n_in,
                              void* d_out, int out_size, void* d_ws, size_t ws_size,
                              hipStream_t stream) {
  const float* query  = (const float*)d_in[0];
  const float* key_in = (const float*)d_in[1];
  const float* value  = (const float*)d_in[2];
  const int*   mask   = (const int*)d_in[3];
  const float* w_q = (const float*)d_in[4];
  const float* b_q = (const float*)d_in[5];
  const float* w_k = (const float*)d_in[6];
  const float* b_k = (const float*)d_in[7];
  const float* w_v = (const float*)d_in[8];
  const float* b_v = (const float*)d_in[9];

  char* ws = (char*)d_ws;
  const size_t proj_elems = (size_t)BATCH * NHEAD * SEQ * HEADD;  // 8388608
  ushort_t* Qp = (ushort_t*)ws;
  ushort_t* Kp = Qp + proj_elems;
  ushort_t* Vp = Kp + proj_elems;          // [B][H][D][S] transposed
  u64* pmask   = (u64*)(ws + 3 * proj_elems * sizeof(ushort_t));

  float* ctx  = (float*)d_out;                         // [B][S][HID]
  float* attn = ctx + (size_t)BATCH * SEQ * HID;       // [B][H][S][S]

  // bf16 prepack scratch lives in d_out's attn region (read by the GEMM,
  // overwritten afterwards by the attn kernel). Sequential + deterministic.
  ushort_t* Xb = (ushort_t*)attn;                         // 3 x 8.4M bf16
  ushort_t* Wb = Xb + (size_t)3 * MROWS * HID;            // 3 x 1M bf16

  prepack_kernel<<<dim3(512, 1, 4), dim3(256), 0, stream>>>(
      query, key_in, value, w_q, w_k, w_v, Xb, Wb, mask, pmask);

  proj_gemm_kernel<<<dim3(HID / 128, MROWS / 128, 3), dim3(256), 0, stream>>>(
      Xb, Wb, b_q, b_k, b_v, Qp, Kp, Vp);

  const size_t lds_attn = (8704 + 17408) * sizeof(ushort_t);  // 52224 B
  fused_attn_kernel<<<dim3(BH * (SEQ / 128)), dim3(256), lds_attn, stream>>>(
      Qp, Kp, Vp, pmask, attn, ctx);
}